// Round 20
// baseline (1255.814 us; speedup 1.0000x reference)
//
#include <hip/hip_runtime.h>
#include <hip/hip_bf16.h>
#include <stdint.h>

typedef short bf16x8 __attribute__((ext_vector_type(8)));
typedef float f32x4  __attribute__((ext_vector_type(4)));
typedef unsigned short u16;

#define T_TOK 4096
#define D_DIM 1024
#define I_DIM 4096
#define NE    9      // 8 routed experts + 1 shared "expert"
#define BK    32

__device__ __forceinline__ u16 f2bf(float f) {
    union { float f; uint32_t u; } v; v.f = f;
    uint32_t u = v.u;
    u += 0x7FFFu + ((u >> 16) & 1u);   // round-to-nearest-even
    return (u16)(u >> 16);
}

// gelu(tanh approx) via sigmoid identity: 0.5v(1+tanh(c)) = v/(1+e^{-2c})
__device__ __forceinline__ float gelu_fast(float v) {
    float c2 = 1.5957691216057308f * (v + 0.044715f * v * v * v);
    return v / (1.0f + __expf(-c2));
}

// async global->LDS, 16B per lane. LDS dest: wave-uniform base + lane*16.
__device__ __forceinline__ void gl16(const void* g, void* l) {
    __builtin_amdgcn_global_load_lds(
        (const __attribute__((address_space(1))) void*)g,
        (__attribute__((address_space(3))) void*)l, 16, 0, 0);
}

// inline-asm ds_read_b128 with literal offset: opaque to compiler alias
// analysis -> no compiler-inserted vmcnt(0) between gl16 and LDS reads.
#define DSR(dst, adr, IMM) \
    asm volatile("ds_read_b128 %0, %1 offset:" #IMM : "=v"(dst) : "v"(adr) : "memory")
#define WAIT_VM(N)   asm volatile("s_waitcnt vmcnt(" #N ")" ::: "memory")
#define WAIT_LG(N)   asm volatile("s_waitcnt lgkmcnt(" #N ")" ::: "memory")

// ---------------------------------------------------------------- init
__global__ void k_init(int* counts) {
    int i = threadIdx.x;
    if (i < 16) counts[i] = (i == 8) ? T_TOK : 0;
}

// ---------------------------------------------------------------- router (+ x->bf16 cast fused)
__global__ __launch_bounds__(256) void k_router(
    const float* __restrict__ x, const float* __restrict__ gw,
    const float* __restrict__ gb,
    int* counts, int* lists, int* tok_e, int* tok_pos, float* tok_w,
    u16* __restrict__ xb)
{
    int wave = threadIdx.x >> 6, lane = threadIdx.x & 63;
    int t = blockIdx.x * 4 + wave;
    const float* xr = x + (size_t)t * D_DIM;
    u16* xbr = xb + (size_t)t * D_DIM;

    float a[8];
#pragma unroll
    for (int e = 0; e < 8; ++e) a[e] = 0.f;
#pragma unroll
    for (int j = 0; j < D_DIM / 64; ++j) {
        int d = lane + 64 * j;
        float xv = xr[d];
        xbr[d] = f2bf(xv);                    // fused cast
        const float4* g = (const float4*)(gw + (size_t)d * 8);
        float4 g0 = g[0], g1 = g[1];
        a[0] += xv * g0.x; a[1] += xv * g0.y; a[2] += xv * g0.z; a[3] += xv * g0.w;
        a[4] += xv * g1.x; a[5] += xv * g1.y; a[6] += xv * g1.z; a[7] += xv * g1.w;
    }
#pragma unroll
    for (int off = 32; off >= 1; off >>= 1)
#pragma unroll
        for (int e = 0; e < 8; ++e) a[e] += __shfl_xor(a[e], off);

    float l[8];
#pragma unroll
    for (int e = 0; e < 8; ++e) l[e] = a[e] + gb[e];
    float mx = l[0];
#pragma unroll
    for (int e = 1; e < 8; ++e) mx = fmaxf(mx, l[e]);
    float p[8], Z = 0.f;
#pragma unroll
    for (int e = 0; e < 8; ++e) { p[e] = expf(l[e] - mx); Z += p[e]; }
#pragma unroll
    for (int e = 0; e < 8; ++e) p[e] /= Z;

    int e0 = 0; float v0 = p[0];
#pragma unroll
    for (int e = 1; e < 8; ++e) if (p[e] > v0) { v0 = p[e]; e0 = e; }
    int e1 = -1; float v1 = -1.f;
#pragma unroll
    for (int e = 0; e < 8; ++e) if (e != e0 && p[e] > v1) { v1 = p[e]; e1 = e; }
    float denom = v0 + v1 + 1e-9f;
    float w0 = v0 / denom, w1 = v1 / denom;

    if (lane == 0) {
        int p0 = atomicAdd(&counts[e0], 1);
        int p1 = atomicAdd(&counts[e1], 1);
        lists[e0 * T_TOK + p0] = t;
        lists[e1 * T_TOK + p1] = t;
        tok_e[2 * t] = e0;  tok_e[2 * t + 1] = e1;
        tok_pos[2 * t] = p0; tok_pos[2 * t + 1] = p1;
        tok_w[2 * t] = w0;  tok_w[2 * t + 1] = w1;
    }
}

// ---------------------------------------------------------------- prefix
__global__ void k_prefix(const int* counts, int* offsets) {
    if (threadIdx.x == 0) {
        int o = 0;
        for (int e = 0; e < NE; ++e) { offsets[e] = o; o += counts[e]; }
        offsets[NE] = o;
    }
}

// ---------------------------------------------------------------- transpose-cast weights v2
// 9 z-slices in ONE launch; 64x64 tile/block; ls[64][65] (2-way-free).
__global__ __launch_bounds__(256) void k_transcast9(
    const float* __restrict__ we, const float* __restrict__ wsh,
    u16* __restrict__ dst, int K, int N)
{
    const float* src = (blockIdx.z == 8) ? wsh : (we + (size_t)blockIdx.z * K * N);
    dst += (size_t)blockIdx.z * N * K;
    __shared__ float ls[64][65];
    int t = threadIdx.x;
    int k0 = blockIdx.y * 64, n0 = blockIdx.x * 64;
    {
        int kr = t >> 2, ng = (t & 3) * 16;
        const float4* s = (const float4*)(src + (size_t)(k0 + kr) * N + n0 + ng);
        float4 v0 = s[0], v1 = s[1], v2 = s[2], v3 = s[3];
        float* d = &ls[kr][ng];
        d[0]  = v0.x; d[1]  = v0.y; d[2]  = v0.z; d[3]  = v0.w;
        d[4]  = v1.x; d[5]  = v1.y; d[6]  = v1.z; d[7]  = v1.w;
        d[8]  = v2.x; d[9]  = v2.y; d[10] = v2.z; d[11] = v2.w;
        d[12] = v3.x; d[13] = v3.y; d[14] = v3.z; d[15] = v3.w;
    }
    __syncthreads();
    int n = t >> 2, kg = (t & 3) * 16;
    u16 o[16];
#pragma unroll
    for (int j = 0; j < 16; ++j) o[j] = f2bf(ls[kg + j][n]);
    u16* dp = &dst[(size_t)(n0 + n) * K + k0 + kg];
    *(bf16x8*)dp       = *(bf16x8*)&o[0];
    *(bf16x8*)(dp + 8) = *(bf16x8*)&o[8];
}

// ---------------------------------------------------------------- grouped GEMM
// GEMM1: NP=2 (128x256 tile), DEPTH=2 -> 48KB LDS, 3 blocks/CU.
//   R19 proved NP=2 cuts FETCH 543->178MB but its depth-3/72KB build lost a
//   resident block (occ 10%) and regressed; depth-2 restores it (R15 measured
//   depth-3's edge at only ~7us). 6 gl16/stage -> vmcnt(6), peel 6/0.
// GEMM2: NP=1, DEPTH=3 -> R15-verbatim (the measured best for it).
// Shared inner machinery for both: alias-opaque asm ds_read_b128 + lgkm(0)
// + sched_barrier, both-sides XOR swizzle (0 conflicts), XCD-group map.
template <int GEMM>
__global__ __launch_bounds__(256, 3)
void k_gemm(const u16* __restrict__ A, const u16* __restrict__ Bt,
            const float* __restrict__ be, const float* __restrict__ bsh,
            const int* __restrict__ counts, const int* __restrict__ offsets,
            const int* __restrict__ lists, void* __restrict__ Cg)
{
    constexpr int K  = (GEMM == 1) ? D_DIM : I_DIM;
    constexpr int N  = (GEMM == 1) ? I_DIM : D_DIM;
    constexpr int NP = (GEMM == 1) ? 2 : 1;  // 128-col panels per block
    constexpr int NT = N / (128 * NP);       // 16 / 8 groups per e
    constexpr int nk = K / BK;               // 32 / 128

    const int bid = blockIdx.x;
    const int g  = ((bid >> 3) >> 5) * 8 + (bid & 7);
    const int mt = (bid >> 3) & 31;
    const int e  = g / NT, nt = g % NT;      // nt in (128*NP)-col units
    const int cnt = counts[e];
    if (mt * 128 >= cnt) return;             // block-uniform: before any barrier
    const int off = offsets[e];

    // 48KB for both variants: GEMM1 = 2x(8KB A)+2x(16KB B); GEMM2 = 3x8+3x8.
    __shared__ __align__(16) u16 lds[24576];
    u16* As0 = lds;
    u16* As1 = lds + 4096;
    u16* As2 = (GEMM == 1) ? nullptr : lds + 8192;
    u16* Bs0 = (GEMM == 1) ? lds + 8192  : lds + 12288;
    u16* Bs1 = (GEMM == 1) ? lds + 16384 : lds + 16384;
    u16* Bs2 = (GEMM == 1) ? nullptr : lds + 20480;

    const int tid = threadIdx.x, w = tid >> 6, l = tid & 63;
    const int wu = __builtin_amdgcn_readfirstlane(w);
    const int wr = w >> 1, wc = w & 1;

    const int scol = ((l & 3) ^ ((l >> 3) & 3)) * 8;        // elements
    const uint32_t rch  = (uint32_t)(((l >> 4) ^ (((l & 15) >> 1) & 3)) << 4);
    const uint32_t aoff = (uint32_t)((wr * 64 + (l & 15)) * 64) + rch;
    const uint32_t boff = (uint32_t)((wc * 64 + (l & 15)) * 64) + rch;
    const uint32_t adr_a0 = (uint32_t)(uintptr_t)As0 + aoff;
    const uint32_t adr_a1 = (uint32_t)(uintptr_t)As1 + aoff;
    const uint32_t adr_a2 = (GEMM == 1) ? 0 : (uint32_t)(uintptr_t)As2 + aoff;
    const uint32_t adr_b0 = (uint32_t)(uintptr_t)Bs0 + boff;
    const uint32_t adr_b1 = (uint32_t)(uintptr_t)Bs1 + boff;
    const uint32_t adr_b2 = (GEMM == 1) ? 0 : (uint32_t)(uintptr_t)Bs2 + boff;

    const u16* Be = Bt + (size_t)e * N * K;
    const u16* aptr[2];
    const u16* bptr[NP][2];
#pragma unroll
    for (int q = 0; q < 2; ++q) {
        int row = mt * 128 + w * 32 + q * 16 + (l >> 2);
        int srow;
        if constexpr (GEMM == 1) {
            if (e == 8) srow = row;          // shared expert: token id == row
            else        srow = lists[e * T_TOK + (row < cnt ? row : cnt - 1)];
        } else {
            srow = off + row;                // contiguous H rows
        }
        aptr[q] = A + (size_t)srow * K + scol;
#pragma unroll
        for (int p = 0; p < NP; ++p)
            bptr[p][q] = Be + (size_t)(nt * 128 * NP + p * 128 + w * 32 + q * 16 + (l >> 2)) * K + scol;
    }

    f32x4 zero = {0.f, 0.f, 0.f, 0.f};
    f32x4 acc[NP][4][4];
#pragma unroll
    for (int p = 0; p < NP; ++p)
#pragma unroll
        for (int m = 0; m < 4; ++m)
#pragma unroll
            for (int n = 0; n < 4; ++n) acc[p][m][n] = zero;

    auto STG = [&](u16* Asb, u16* Bsb, int kt) {
        const int ko = kt * BK;
#pragma unroll
        for (int q = 0; q < 2; ++q) {
            gl16(aptr[q] + ko, Asb + wu * 1024 + q * 512);
#pragma unroll
            for (int p = 0; p < NP; ++p)
                gl16(bptr[p][q] + ko, Bsb + p * 4096 + wu * 1024 + q * 512);
        }
    };
    // phase body: read fragments (asm), read-done barrier, restage, MFMA
    auto RDM = [&](uint32_t aA, uint32_t aB, bool st, u16* sA, u16* sB, int knext) {
        bf16x8 fa[4], fb[4], fb2[4];
        DSR(fa[0], aA, 0);    DSR(fa[1], aA, 1024);
        DSR(fa[2], aA, 2048); DSR(fa[3], aA, 3072);
        DSR(fb[0], aB, 0);    DSR(fb[1], aB, 1024);
        DSR(fb[2], aB, 2048); DSR(fb[3], aB, 3072);
        if constexpr (NP == 2) {
            // panel 1 at BYTE offset 8192 (4096 u16) in the Bs buffer
            DSR(fb2[0], aB, 8192);  DSR(fb2[1], aB, 9216);
            DSR(fb2[2], aB, 10240); DSR(fb2[3], aB, 11264);
        }
        WAIT_LG(0);
        __builtin_amdgcn_sched_barrier(0);
        __builtin_amdgcn_s_barrier();    // all waves done reading this buffer
        if (st) STG(sA, sB, knext);      // refill it; loads fly across barriers
        __builtin_amdgcn_s_setprio(1);
#pragma unroll
        for (int m = 0; m < 4; ++m)
#pragma unroll
            for (int n = 0; n < 4; ++n)
                acc[0][m][n] = __builtin_amdgcn_mfma_f32_16x16x32_bf16(fa[m], fb[n], acc[0][m][n], 0, 0, 0);
        if constexpr (NP == 2) {
#pragma unroll
            for (int m = 0; m < 4; ++m)
#pragma unroll
                for (int n = 0; n < 4; ++n)
                    acc[1][m][n] = __builtin_amdgcn_mfma_f32_16x16x32_bf16(fa[m], fb2[n], acc[1][m][n], 0, 0, 0);
        }
        __builtin_amdgcn_s_setprio(0);
    };

    if constexpr (GEMM == 1) {
        // depth-2, 6 loads/stage: counted vmcnt(6), peel 6/0 (R10 schedule).
        STG(As0, Bs0, 0);
        STG(As1, Bs1, 1);
        for (int kt = 0; kt + 2 < nk; kt += 2) {
            WAIT_VM(6);  __builtin_amdgcn_s_barrier();
            RDM(adr_a0, adr_b0, true, As0, Bs0, kt + 2);
            WAIT_VM(6);  __builtin_amdgcn_s_barrier();
            RDM(adr_a1, adr_b1, true, As1, Bs1, kt + 3);
        }
        WAIT_VM(6);  __builtin_amdgcn_s_barrier();
        RDM(adr_a0, adr_b0, false, As0, Bs0, 0);
        WAIT_VM(0);  __builtin_amdgcn_s_barrier();
        RDM(adr_a1, adr_b1, false, As1, Bs1, 0);
    } else {
        // depth-3, 4 loads/stage: counted vmcnt(8), peel 8/4/0 (R15 schedule).
        STG(As0, Bs0, 0);
        STG(As1, Bs1, 1);
        STG(As2, Bs2, 2);
        for (int b = 0; b + 5 < nk; b += 3) {
            WAIT_VM(8); __builtin_amdgcn_s_barrier();
            RDM(adr_a0, adr_b0, true, As0, Bs0, b + 3);
            WAIT_VM(8); __builtin_amdgcn_s_barrier();
            RDM(adr_a1, adr_b1, true, As1, Bs1, b + 4);
            WAIT_VM(8); __builtin_amdgcn_s_barrier();
            RDM(adr_a2, adr_b2, true, As2, Bs2, b + 5);
        }
        WAIT_VM(8); __builtin_amdgcn_s_barrier();
        RDM(adr_a0, adr_b0, true, As0, Bs0, nk - 2);
        WAIT_VM(8); __builtin_amdgcn_s_barrier();
        RDM(adr_a1, adr_b1, true, As1, Bs1, nk - 1);
        WAIT_VM(8); __builtin_amdgcn_s_barrier();
        RDM(adr_a2, adr_b2, false, As2, Bs2, 0);
        WAIT_VM(4); __builtin_amdgcn_s_barrier();
        RDM(adr_a0, adr_b0, false, As0, Bs0, 0);
        WAIT_VM(0); __builtin_amdgcn_s_barrier();
        RDM(adr_a1, adr_b1, false, As1, Bs1, 0);
    }

    // ---- epilogue.  D mapping: col = lane&15, row = (lane>>4)*4 + reg
    const float* bias = (e == 8) ? bsh : (be + (size_t)e * N);
#pragma unroll
    for (int p = 0; p < NP; ++p) {
#pragma unroll
        for (int m = 0; m < 4; ++m) {
            int pbase = mt * 128 + wr * 64 + m * 16 + (l >> 4) * 4;
#pragma unroll
            for (int n = 0; n < 4; ++n) {
                int gcol = nt * 128 * NP + p * 128 + wc * 64 + n * 16 + (l & 15);
                float bv = bias[gcol];
#pragma unroll
                for (int r = 0; r < 4; ++r) {
                    int pos = pbase + r;
                    if (pos < cnt) {
                        float v = acc[p][m][n][r] + bv;
                        if constexpr (GEMM == 1)
                            ((u16*)Cg)[(size_t)(off + pos) * N + gcol] = f2bf(gelu_fast(v));
                        else
                            ((float*)Cg)[(size_t)(off + pos) * N + gcol] = v;
                    }
                }
            }
        }
    }
}

// ---------------------------------------------------------------- combine
__global__ __launch_bounds__(256) void k_combine(
    const float* __restrict__ x, const float* __restrict__ P,
    const int* __restrict__ offsets, const int* __restrict__ tok_e,
    const int* __restrict__ tok_pos, const float* __restrict__ tok_w,
    float* __restrict__ out)
{
    int t = blockIdx.x;
    int e0 = tok_e[2 * t], e1 = tok_e[2 * t + 1];
    int r0 = offsets[e0] + tok_pos[2 * t];
    int r1 = offsets[e1] + tok_pos[2 * t + 1];
    int rs = offsets[8] + t;
    float w0 = tok_w[2 * t], w1 = tok_w[2 * t + 1];
    int i = threadIdx.x * 4;

    float4 xv = *(const float4*)(x + (size_t)t * D_DIM + i);
    float4 ps = *(const float4*)(P + (size_t)rs * D_DIM + i);
    float4 p0 = *(const float4*)(P + (size_t)r0 * D_DIM + i);
    float4 p1 = *(const float4*)(P + (size_t)r1 * D_DIM + i);
    float4 o;
    o.x = xv.x + ps.x + w0 * p0.x + w1 * p1.x;
    o.y = xv.y + ps.y + w0 * p0.y + w1 * p1.y;
    o.z = xv.z + ps.z + w0 * p0.z + w1 * p1.z;
    o.w = xv.w + ps.w + w0 * p0.w + w1 * p1.w;
    *(float4*)(out + (size_t)t * D_DIM + i) = o;
}

// ---------------------------------------------------------------- launch
extern "C" void kernel_launch(void* const* d_in, const int* in_sizes, int n_in,
                              void* d_out, int out_size, void* d_ws, size_t ws_size,
                              hipStream_t stream)
{
    const float* x   = (const float*)d_in[0];
    const float* gw  = (const float*)d_in[1];
    const float* gb  = (const float*)d_in[2];
    const float* sw1 = (const float*)d_in[3];
    const float* sb1 = (const float*)d_in[4];
    const float* sw2 = (const float*)d_in[5];
    const float* sb2 = (const float*)d_in[6];
    const float* ew1 = (const float*)d_in[7];
    const float* eb1 = (const float*)d_in[8];
    const float* ew2 = (const float*)d_in[9];
    const float* eb2 = (const float*)d_in[10];

    char* w = (char*)d_ws;
    int* counts  = (int*)w;                       // 16 ints
    int* offsets = (int*)(w + 64);                // 16 ints
    int* tok_e   = (int*)(w + 2048);              // 2T ints
    int* tok_pos = tok_e + 2 * T_TOK;             // 2T ints
    float* tok_w = (float*)(tok_pos + 2 * T_TOK); // 2T floats
    int* lists   = (int*)(tok_w + 2 * T_TOK);     // 8T ints (routed only)

    size_t o = (size_t)1 << 20;                   // 1MB: small buffers above
    u16* xb  = (u16*)(w + o);                     // 4096 x 1024 bf16 (8MB)
    o += (size_t)T_TOK * D_DIM * 2;
    u16* H   = (u16*)(w + o);                     // 12288 x 4096 bf16 (96MB)
    o += (size_t)3 * T_TOK * I_DIM * 2;
    u16* Wt  = (u16*)(w + o);                     // 9 x 4096 x 1024 bf16 (72MB), W1t then W2t
    o += (size_t)NE * I_DIM * D_DIM * 2;
    float* P = (float*)(w + o);                   // 12288 x 1024 f32 (48MB)

    k_init<<<1, 64, 0, stream>>>(counts);

    // W1^T: f32 [K=1024][N=4096] -> bf16 [4096][1024], 9 slices in one launch
    k_transcast9<<<dim3(I_DIM / 64, D_DIM / 64, 9), 256, 0, stream>>>(
        ew1, sw1, Wt, D_DIM, I_DIM);

    // router (writes xb as a side product)
    k_router<<<T_TOK / 4, 256, 0, stream>>>(x, gw, gb, counts, lists, tok_e, tok_pos, tok_w, xb);
    k_prefix<<<1, 64, 0, stream>>>(counts, offsets);

    // GEMM1: H = gelu(Xg @ W1 + b1), N = I.  128x256 tiles (NP=2, depth-2).
    // Groups = 9*16 = 144 (%8==0), grid = 144*32 = 4608.
    k_gemm<1><<<NE * (I_DIM / 256) * 32, 256, 0, stream>>>(
        xb, Wt, eb1, sb1, counts, offsets, lists, (void*)H);

    // W2^T: f32 [K=4096][N=1024] -> bf16 [1024][4096]  (aliases W1t; stream-ordered)
    k_transcast9<<<dim3(D_DIM / 64, I_DIM / 64, 9), 256, 0, stream>>>(
        ew2, sw2, Wt, I_DIM, D_DIM);

    // GEMM2: P = H @ W2 + b2, N = D.  R15-verbatim 128x128 depth-3.
    k_gemm<2><<<NE * (D_DIM / 128) * 32, 256, 0, stream>>>(
        H, Wt, eb2, sb2, counts, offsets, lists, (void*)P);

    k_combine<<<T_TOK, 256, 0, stream>>>(x, P, offsets, tok_e, tok_pos, tok_w, (float*)d_out);
}

// Round 21
// 566.663 us; speedup vs baseline: 2.2162x; 2.2162x over previous
//
#include <hip/hip_runtime.h>
#include <hip/hip_bf16.h>
#include <stdint.h>

typedef short bf16x8 __attribute__((ext_vector_type(8)));
typedef float f32x4  __attribute__((ext_vector_type(4)));
typedef unsigned short u16;

#define T_TOK 4096
#define D_DIM 1024
#define I_DIM 4096
#define NE    9      // 8 routed experts + 1 shared "expert"
#define BK    32

__device__ __forceinline__ u16 f2bf(float f) {
    union { float f; uint32_t u; } v; v.f = f;
    uint32_t u = v.u;
    u += 0x7FFFu + ((u >> 16) & 1u);   // round-to-nearest-even
    return (u16)(u >> 16);
}

// gelu(tanh approx) via sigmoid identity: 0.5v(1+tanh(c)) = v/(1+e^{-2c})
__device__ __forceinline__ float gelu_fast(float v) {
    float c2 = 1.5957691216057308f * (v + 0.044715f * v * v * v);
    return v / (1.0f + __expf(-c2));
}

// async global->LDS, 16B per lane. LDS dest: wave-uniform base + lane*16.
__device__ __forceinline__ void gl16(const void* g, void* l) {
    __builtin_amdgcn_global_load_lds(
        (const __attribute__((address_space(1))) void*)g,
        (__attribute__((address_space(3))) void*)l, 16, 0, 0);
}

// inline-asm ds_read_b128 with literal offset: opaque to compiler alias
// analysis -> no compiler-inserted vmcnt(0) between gl16 and LDS reads.
#define DSR(dst, adr, IMM) \
    asm volatile("ds_read_b128 %0, %1 offset:" #IMM : "=v"(dst) : "v"(adr) : "memory")
#define WAIT_VM(N)   asm volatile("s_waitcnt vmcnt(" #N ")" ::: "memory")
#define WAIT_LG(N)   asm volatile("s_waitcnt lgkmcnt(" #N ")" ::: "memory")

// ---------------------------------------------------------------- init
__global__ void k_init(int* counts) {
    int i = threadIdx.x;
    if (i < 16) counts[i] = (i == 8) ? T_TOK : 0;
}

// ---------------------------------------------------------------- router (+ x->bf16 cast fused)
__global__ __launch_bounds__(256) void k_router(
    const float* __restrict__ x, const float* __restrict__ gw,
    const float* __restrict__ gb,
    int* counts, int* lists, int* tok_e, int* tok_pos, float* tok_w,
    u16* __restrict__ xb)
{
    int wave = threadIdx.x >> 6, lane = threadIdx.x & 63;
    int t = blockIdx.x * 4 + wave;
    const float* xr = x + (size_t)t * D_DIM;
    u16* xbr = xb + (size_t)t * D_DIM;

    float a[8];
#pragma unroll
    for (int e = 0; e < 8; ++e) a[e] = 0.f;
#pragma unroll
    for (int j = 0; j < D_DIM / 64; ++j) {
        int d = lane + 64 * j;
        float xv = xr[d];
        xbr[d] = f2bf(xv);                    // fused cast
        const float4* g = (const float4*)(gw + (size_t)d * 8);
        float4 g0 = g[0], g1 = g[1];
        a[0] += xv * g0.x; a[1] += xv * g0.y; a[2] += xv * g0.z; a[3] += xv * g0.w;
        a[4] += xv * g1.x; a[5] += xv * g1.y; a[6] += xv * g1.z; a[7] += xv * g1.w;
    }
#pragma unroll
    for (int off = 32; off >= 1; off >>= 1)
#pragma unroll
        for (int e = 0; e < 8; ++e) a[e] += __shfl_xor(a[e], off);

    float l[8];
#pragma unroll
    for (int e = 0; e < 8; ++e) l[e] = a[e] + gb[e];
    float mx = l[0];
#pragma unroll
    for (int e = 1; e < 8; ++e) mx = fmaxf(mx, l[e]);
    float p[8], Z = 0.f;
#pragma unroll
    for (int e = 0; e < 8; ++e) { p[e] = expf(l[e] - mx); Z += p[e]; }
#pragma unroll
    for (int e = 0; e < 8; ++e) p[e] /= Z;

    int e0 = 0; float v0 = p[0];
#pragma unroll
    for (int e = 1; e < 8; ++e) if (p[e] > v0) { v0 = p[e]; e0 = e; }
    int e1 = -1; float v1 = -1.f;
#pragma unroll
    for (int e = 0; e < 8; ++e) if (e != e0 && p[e] > v1) { v1 = p[e]; e1 = e; }
    float denom = v0 + v1 + 1e-9f;
    float w0 = v0 / denom, w1 = v1 / denom;

    if (lane == 0) {
        int p0 = atomicAdd(&counts[e0], 1);
        int p1 = atomicAdd(&counts[e1], 1);
        lists[e0 * T_TOK + p0] = t;
        lists[e1 * T_TOK + p1] = t;
        tok_e[2 * t] = e0;  tok_e[2 * t + 1] = e1;
        tok_pos[2 * t] = p0; tok_pos[2 * t + 1] = p1;
        tok_w[2 * t] = w0;  tok_w[2 * t + 1] = w1;
    }
}

// ---------------------------------------------------------------- prefix
__global__ void k_prefix(const int* counts, int* offsets) {
    if (threadIdx.x == 0) {
        int o = 0;
        for (int e = 0; e < NE; ++e) { offsets[e] = o; o += counts[e]; }
        offsets[NE] = o;
    }
}

// ---------------------------------------------------------------- transpose-cast weights v2
// 9 z-slices in ONE launch; 64x64 tile/block; ls[64][65] (2-way-free).
__global__ __launch_bounds__(256) void k_transcast9(
    const float* __restrict__ we, const float* __restrict__ wsh,
    u16* __restrict__ dst, int K, int N)
{
    const float* src = (blockIdx.z == 8) ? wsh : (we + (size_t)blockIdx.z * K * N);
    dst += (size_t)blockIdx.z * N * K;
    __shared__ float ls[64][65];
    int t = threadIdx.x;
    int k0 = blockIdx.y * 64, n0 = blockIdx.x * 64;
    {
        int kr = t >> 2, ng = (t & 3) * 16;
        const float4* s = (const float4*)(src + (size_t)(k0 + kr) * N + n0 + ng);
        float4 v0 = s[0], v1 = s[1], v2 = s[2], v3 = s[3];
        float* d = &ls[kr][ng];
        d[0]  = v0.x; d[1]  = v0.y; d[2]  = v0.z; d[3]  = v0.w;
        d[4]  = v1.x; d[5]  = v1.y; d[6]  = v1.z; d[7]  = v1.w;
        d[8]  = v2.x; d[9]  = v2.y; d[10] = v2.z; d[11] = v2.w;
        d[12] = v3.x; d[13] = v3.y; d[14] = v3.z; d[15] = v3.w;
    }
    __syncthreads();
    int n = t >> 2, kg = (t & 3) * 16;
    u16 o[16];
#pragma unroll
    for (int j = 0; j < 16; ++j) o[j] = f2bf(ls[kg + j][n]);
    u16* dp = &dst[(size_t)(n0 + n) * K + k0 + kg];
    *(bf16x8*)dp       = *(bf16x8*)&o[0];
    *(bf16x8*)(dp + 8) = *(bf16x8*)&o[8];
}

// ---------------------------------------------------------------- grouped GEMM
// R17-verbatim (measured best: 566.2us total). 128x128, BK=32, 4 waves 2x2,
// depth-3 buffer rotation, counted vmcnt(8) + raw s_barrier, alias-opaque
// asm ds_read_b128 + lgkm(0)+sched_barrier, both-sides XOR swizzle (0
// conflicts), XCD-group map (all 32 m-slots of one (e,nt) panel on one XCD).
// GEMM==1: A=xb gathered via lists (K=1024,N=4096), epi gelu->bf16 H.
// GEMM==2: A=H contiguous (K=4096,N=1024), epi +bias->f32 P.
template <int GEMM>
__global__ __launch_bounds__(256, 3)
void k_gemm(const u16* __restrict__ A, const u16* __restrict__ Bt,
            const float* __restrict__ be, const float* __restrict__ bsh,
            const int* __restrict__ counts, const int* __restrict__ offsets,
            const int* __restrict__ lists, void* __restrict__ Cg)
{
    constexpr int K  = (GEMM == 1) ? D_DIM : I_DIM;
    constexpr int N  = (GEMM == 1) ? I_DIM : D_DIM;
    constexpr int NT = N / 128;              // 32 / 8
    constexpr int nk = K / BK;               // 32 / 128 (both == 2 mod 3)

    const int bid = blockIdx.x;
    const int g  = ((bid >> 3) >> 5) * 8 + (bid & 7);
    const int mt = (bid >> 3) & 31;
    const int e  = g / NT, nt = g % NT;
    const int cnt = counts[e];
    if (mt * 128 >= cnt) return;             // block-uniform: before any barrier
    const int off = offsets[e];

    __shared__ __align__(16) u16 As0[4096], As1[4096], As2[4096];
    __shared__ __align__(16) u16 Bs0[4096], Bs1[4096], Bs2[4096];

    const int tid = threadIdx.x, w = tid >> 6, l = tid & 63;
    const int wu = __builtin_amdgcn_readfirstlane(w);
    const int wr = w >> 1, wc = w & 1;

    const int scol = ((l & 3) ^ ((l >> 3) & 3)) * 8;        // elements
    const uint32_t rch  = (uint32_t)(((l >> 4) ^ (((l & 15) >> 1) & 3)) << 4);
    const uint32_t aoff = (uint32_t)((wr * 64 + (l & 15)) * 64) + rch;
    const uint32_t boff = (uint32_t)((wc * 64 + (l & 15)) * 64) + rch;
    const uint32_t adr_a0 = (uint32_t)(uintptr_t)As0 + aoff;
    const uint32_t adr_a1 = (uint32_t)(uintptr_t)As1 + aoff;
    const uint32_t adr_a2 = (uint32_t)(uintptr_t)As2 + aoff;
    const uint32_t adr_b0 = (uint32_t)(uintptr_t)Bs0 + boff;
    const uint32_t adr_b1 = (uint32_t)(uintptr_t)Bs1 + boff;
    const uint32_t adr_b2 = (uint32_t)(uintptr_t)Bs2 + boff;

    const u16* Be = Bt + (size_t)e * N * K;
    const u16* aptr[2];
    const u16* bptr[2];
#pragma unroll
    for (int q = 0; q < 2; ++q) {
        int row = mt * 128 + w * 32 + q * 16 + (l >> 2);
        int srow;
        if constexpr (GEMM == 1) {
            if (e == 8) srow = row;          // shared expert: token id == row
            else        srow = lists[e * T_TOK + (row < cnt ? row : cnt - 1)];
        } else {
            srow = off + row;                // contiguous H rows
        }
        aptr[q] = A + (size_t)srow * K + scol;
        bptr[q] = Be + (size_t)(nt * 128 + w * 32 + q * 16 + (l >> 2)) * K + scol;
    }

    f32x4 zero = {0.f, 0.f, 0.f, 0.f};
    f32x4 acc[4][4];
#pragma unroll
    for (int m = 0; m < 4; ++m)
#pragma unroll
        for (int n = 0; n < 4; ++n) acc[m][n] = zero;

    auto STG = [&](u16* Asb, u16* Bsb, int kt) {
        const int ko = kt * BK;
#pragma unroll
        for (int q = 0; q < 2; ++q) {
            gl16(aptr[q] + ko, Asb + wu * 1024 + q * 512);
            gl16(bptr[q] + ko, Bsb + wu * 1024 + q * 512);
        }
    };
    auto RDM = [&](uint32_t aA, uint32_t aB, bool st, u16* sA, u16* sB, int knext) {
        bf16x8 fa[4], fb[4];
        DSR(fa[0], aA, 0);    DSR(fa[1], aA, 1024);
        DSR(fa[2], aA, 2048); DSR(fa[3], aA, 3072);
        DSR(fb[0], aB, 0);    DSR(fb[1], aB, 1024);
        DSR(fb[2], aB, 2048); DSR(fb[3], aB, 3072);
        WAIT_LG(0);
        __builtin_amdgcn_sched_barrier(0);
        __builtin_amdgcn_s_barrier();    // all waves done reading this buffer
        if (st) STG(sA, sB, knext);      // refill it; loads fly across barriers
        __builtin_amdgcn_s_setprio(1);
#pragma unroll
        for (int m = 0; m < 4; ++m)
#pragma unroll
            for (int n = 0; n < 4; ++n)
                acc[m][n] = __builtin_amdgcn_mfma_f32_16x16x32_bf16(fa[m], fb[n], acc[m][n], 0, 0, 0);
        __builtin_amdgcn_s_setprio(0);
    };

    STG(As0, Bs0, 0);
    STG(As1, Bs1, 1);
    STG(As2, Bs2, 2);
    for (int b = 0; b + 5 < nk; b += 3) {
        WAIT_VM(8); __builtin_amdgcn_s_barrier();
        RDM(adr_a0, adr_b0, true, As0, Bs0, b + 3);
        WAIT_VM(8); __builtin_amdgcn_s_barrier();
        RDM(adr_a1, adr_b1, true, As1, Bs1, b + 4);
        WAIT_VM(8); __builtin_amdgcn_s_barrier();
        RDM(adr_a2, adr_b2, true, As2, Bs2, b + 5);
    }
    WAIT_VM(8); __builtin_amdgcn_s_barrier();
    RDM(adr_a0, adr_b0, true, As0, Bs0, nk - 2);
    WAIT_VM(8); __builtin_amdgcn_s_barrier();
    RDM(adr_a1, adr_b1, true, As1, Bs1, nk - 1);
    WAIT_VM(8); __builtin_amdgcn_s_barrier();
    RDM(adr_a2, adr_b2, false, As2, Bs2, 0);
    WAIT_VM(4); __builtin_amdgcn_s_barrier();
    RDM(adr_a0, adr_b0, false, As0, Bs0, 0);
    WAIT_VM(0); __builtin_amdgcn_s_barrier();
    RDM(adr_a1, adr_b1, false, As1, Bs1, 0);

    // ---- epilogue.  D mapping: col = lane&15, row = (lane>>4)*4 + reg
    const float* bias = (e == 8) ? bsh : (be + (size_t)e * N);
#pragma unroll
    for (int m = 0; m < 4; ++m) {
        int pbase = mt * 128 + wr * 64 + m * 16 + (l >> 4) * 4;
#pragma unroll
        for (int n = 0; n < 4; ++n) {
            int gcol = nt * 128 + wc * 64 + n * 16 + (l & 15);
            float bv = bias[gcol];
#pragma unroll
            for (int r = 0; r < 4; ++r) {
                int pos = pbase + r;
                if (pos < cnt) {
                    float v = acc[m][n][r] + bv;
                    if constexpr (GEMM == 1)
                        ((u16*)Cg)[(size_t)(off + pos) * N + gcol] = f2bf(gelu_fast(v));
                    else
                        ((float*)Cg)[(size_t)(off + pos) * N + gcol] = v;
                }
            }
        }
    }
}

// ---------------------------------------------------------------- combine
__global__ __launch_bounds__(256) void k_combine(
    const float* __restrict__ x, const float* __restrict__ P,
    const int* __restrict__ offsets, const int* __restrict__ tok_e,
    const int* __restrict__ tok_pos, const float* __restrict__ tok_w,
    float* __restrict__ out)
{
    int t = blockIdx.x;
    int e0 = tok_e[2 * t], e1 = tok_e[2 * t + 1];
    int r0 = offsets[e0] + tok_pos[2 * t];
    int r1 = offsets[e1] + tok_pos[2 * t + 1];
    int rs = offsets[8] + t;
    float w0 = tok_w[2 * t], w1 = tok_w[2 * t + 1];
    int i = threadIdx.x * 4;

    float4 xv = *(const float4*)(x + (size_t)t * D_DIM + i);
    float4 ps = *(const float4*)(P + (size_t)rs * D_DIM + i);
    float4 p0 = *(const float4*)(P + (size_t)r0 * D_DIM + i);
    float4 p1 = *(const float4*)(P + (size_t)r1 * D_DIM + i);
    float4 o;
    o.x = xv.x + ps.x + w0 * p0.x + w1 * p1.x;
    o.y = xv.y + ps.y + w0 * p0.y + w1 * p1.y;
    o.z = xv.z + ps.z + w0 * p0.z + w1 * p1.z;
    o.w = xv.w + ps.w + w0 * p0.w + w1 * p1.w;
    *(float4*)(out + (size_t)t * D_DIM + i) = o;
}

// ---------------------------------------------------------------- launch
extern "C" void kernel_launch(void* const* d_in, const int* in_sizes, int n_in,
                              void* d_out, int out_size, void* d_ws, size_t ws_size,
                              hipStream_t stream)
{
    const float* x   = (const float*)d_in[0];
    const float* gw  = (const float*)d_in[1];
    const float* gb  = (const float*)d_in[2];
    const float* sw1 = (const float*)d_in[3];
    const float* sb1 = (const float*)d_in[4];
    const float* sw2 = (const float*)d_in[5];
    const float* sb2 = (const float*)d_in[6];
    const float* ew1 = (const float*)d_in[7];
    const float* eb1 = (const float*)d_in[8];
    const float* ew2 = (const float*)d_in[9];
    const float* eb2 = (const float*)d_in[10];

    char* w = (char*)d_ws;
    int* counts  = (int*)w;                       // 16 ints
    int* offsets = (int*)(w + 64);                // 16 ints
    int* tok_e   = (int*)(w + 2048);              // 2T ints
    int* tok_pos = tok_e + 2 * T_TOK;             // 2T ints
    float* tok_w = (float*)(tok_pos + 2 * T_TOK); // 2T floats
    int* lists   = (int*)(tok_w + 2 * T_TOK);     // 8T ints (routed only)

    size_t o = (size_t)1 << 20;                   // 1MB: small buffers above
    u16* xb  = (u16*)(w + o);                     // 4096 x 1024 bf16 (8MB)
    o += (size_t)T_TOK * D_DIM * 2;
    u16* H   = (u16*)(w + o);                     // 12288 x 4096 bf16 (96MB)
    o += (size_t)3 * T_TOK * I_DIM * 2;
    u16* Wt  = (u16*)(w + o);                     // 9 x 4096 x 1024 bf16 (72MB), W1t then W2t
    o += (size_t)NE * I_DIM * D_DIM * 2;
    float* P = (float*)(w + o);                   // 12288 x 1024 f32 (48MB)

    k_init<<<1, 64, 0, stream>>>(counts);

    // W1^T: f32 [K=1024][N=4096] -> bf16 [4096][1024], 9 slices in one launch
    k_transcast9<<<dim3(I_DIM / 64, D_DIM / 64, 9), 256, 0, stream>>>(
        ew1, sw1, Wt, D_DIM, I_DIM);

    // router (writes xb as a side product)
    k_router<<<T_TOK / 4, 256, 0, stream>>>(x, gw, gb, counts, lists, tok_e, tok_pos, tok_w, xb);
    k_prefix<<<1, 64, 0, stream>>>(counts, offsets);

    // GEMM1: H = gelu(Xg @ W1 + b1), N = I.  XCD-grouped 1-tile blocks.
    k_gemm<1><<<NE * (I_DIM / 128) * 32, 256, 0, stream>>>(
        xb, Wt, eb1, sb1, counts, offsets, lists, (void*)H);

    // W2^T: f32 [K=4096][N=1024] -> bf16 [1024][4096]  (aliases W1t; stream-ordered)
    k_transcast9<<<dim3(D_DIM / 64, I_DIM / 64, 9), 256, 0, stream>>>(
        ew2, sw2, Wt, I_DIM, D_DIM);

    // GEMM2: P = H @ W2 + b2, N = D.  R15-verbatim 128x128, XCD-grouped.
    k_gemm<2><<<NE * (D_DIM / 128) * 32, 256, 0, stream>>>(
        H, Wt, eb2, sb2, counts, offsets, lists, (void*)P);

    k_combine<<<T_TOK, 256, 0, stream>>>(x, P, offsets, tok_e, tok_pos, tok_w, (float*)d_out);
}

// Round 22
// 558.373 us; speedup vs baseline: 2.2491x; 1.0148x over previous
//
#include <hip/hip_runtime.h>
#include <hip/hip_bf16.h>
#include <stdint.h>

typedef short bf16x8 __attribute__((ext_vector_type(8)));
typedef float f32x4  __attribute__((ext_vector_type(4)));
typedef unsigned short u16;

#define T_TOK 4096
#define D_DIM 1024
#define I_DIM 4096
#define NE    9      // 8 routed experts + 1 shared "expert"
#define BK    32

__device__ __forceinline__ u16 f2bf(float f) {
    union { float f; uint32_t u; } v; v.f = f;
    uint32_t u = v.u;
    u += 0x7FFFu + ((u >> 16) & 1u);   // round-to-nearest-even
    return (u16)(u >> 16);
}

// gelu(tanh approx) via sigmoid identity: 0.5v(1+tanh(c)) = v/(1+e^{-2c})
__device__ __forceinline__ float gelu_fast(float v) {
    float c2 = 1.5957691216057308f * (v + 0.044715f * v * v * v);
    return v / (1.0f + __expf(-c2));
}

// async global->LDS, 16B per lane. LDS dest: wave-uniform base + lane*16.
__device__ __forceinline__ void gl16(const void* g, void* l) {
    __builtin_amdgcn_global_load_lds(
        (const __attribute__((address_space(1))) void*)g,
        (__attribute__((address_space(3))) void*)l, 16, 0, 0);
}

// inline-asm ds_read_b128 with literal offset: opaque to compiler alias
// analysis -> no compiler-inserted vmcnt(0) between gl16 and LDS reads.
#define DSR(dst, adr, IMM) \
    asm volatile("ds_read_b128 %0, %1 offset:" #IMM : "=v"(dst) : "v"(adr) : "memory")
#define WAIT_VM(N)   asm volatile("s_waitcnt vmcnt(" #N ")" ::: "memory")
#define WAIT_LG(N)   asm volatile("s_waitcnt lgkmcnt(" #N ")" ::: "memory")

// ---------------------------------------------------------------- init
__global__ void k_init(int* counts) {
    int i = threadIdx.x;
    if (i < 16) counts[i] = (i == 8) ? T_TOK : 0;
}

// ---------------------------------------------------------------- router (+ x->bf16 cast fused)
__global__ __launch_bounds__(256) void k_router(
    const float* __restrict__ x, const float* __restrict__ gw,
    const float* __restrict__ gb,
    int* counts, int* lists, int* tok_e, int* tok_pos, float* tok_w,
    u16* __restrict__ xb)
{
    int wave = threadIdx.x >> 6, lane = threadIdx.x & 63;
    int t = blockIdx.x * 4 + wave;
    const float* xr = x + (size_t)t * D_DIM;
    u16* xbr = xb + (size_t)t * D_DIM;

    float a[8];
#pragma unroll
    for (int e = 0; e < 8; ++e) a[e] = 0.f;
#pragma unroll
    for (int j = 0; j < D_DIM / 64; ++j) {
        int d = lane + 64 * j;
        float xv = xr[d];
        xbr[d] = f2bf(xv);                    // fused cast
        const float4* g = (const float4*)(gw + (size_t)d * 8);
        float4 g0 = g[0], g1 = g[1];
        a[0] += xv * g0.x; a[1] += xv * g0.y; a[2] += xv * g0.z; a[3] += xv * g0.w;
        a[4] += xv * g1.x; a[5] += xv * g1.y; a[6] += xv * g1.z; a[7] += xv * g1.w;
    }
#pragma unroll
    for (int off = 32; off >= 1; off >>= 1)
#pragma unroll
        for (int e = 0; e < 8; ++e) a[e] += __shfl_xor(a[e], off);

    float l[8];
#pragma unroll
    for (int e = 0; e < 8; ++e) l[e] = a[e] + gb[e];
    float mx = l[0];
#pragma unroll
    for (int e = 1; e < 8; ++e) mx = fmaxf(mx, l[e]);
    float p[8], Z = 0.f;
#pragma unroll
    for (int e = 0; e < 8; ++e) { p[e] = expf(l[e] - mx); Z += p[e]; }
#pragma unroll
    for (int e = 0; e < 8; ++e) p[e] /= Z;

    int e0 = 0; float v0 = p[0];
#pragma unroll
    for (int e = 1; e < 8; ++e) if (p[e] > v0) { v0 = p[e]; e0 = e; }
    int e1 = -1; float v1 = -1.f;
#pragma unroll
    for (int e = 0; e < 8; ++e) if (e != e0 && p[e] > v1) { v1 = p[e]; e1 = e; }
    float denom = v0 + v1 + 1e-9f;
    float w0 = v0 / denom, w1 = v1 / denom;

    if (lane == 0) {
        int p0 = atomicAdd(&counts[e0], 1);
        int p1 = atomicAdd(&counts[e1], 1);
        lists[e0 * T_TOK + p0] = t;
        lists[e1 * T_TOK + p1] = t;
        tok_e[2 * t] = e0;  tok_e[2 * t + 1] = e1;
        tok_pos[2 * t] = p0; tok_pos[2 * t + 1] = p1;
        tok_w[2 * t] = w0;  tok_w[2 * t + 1] = w1;
    }
}

// ---------------------------------------------------------------- prefix
__global__ void k_prefix(const int* counts, int* offsets) {
    if (threadIdx.x == 0) {
        int o = 0;
        for (int e = 0; e < NE; ++e) { offsets[e] = o; o += counts[e]; }
        offsets[NE] = o;
    }
}

// ---------------------------------------------------------------- transpose-cast weights v2
// 9 z-slices in ONE launch; 64x64 tile/block; ls[64][65] (2-way-free).
__global__ __launch_bounds__(256) void k_transcast9(
    const float* __restrict__ we, const float* __restrict__ wsh,
    u16* __restrict__ dst, int K, int N)
{
    const float* src = (blockIdx.z == 8) ? wsh : (we + (size_t)blockIdx.z * K * N);
    dst += (size_t)blockIdx.z * N * K;
    __shared__ float ls[64][65];
    int t = threadIdx.x;
    int k0 = blockIdx.y * 64, n0 = blockIdx.x * 64;
    {
        int kr = t >> 2, ng = (t & 3) * 16;
        const float4* s = (const float4*)(src + (size_t)(k0 + kr) * N + n0 + ng);
        float4 v0 = s[0], v1 = s[1], v2 = s[2], v3 = s[3];
        float* d = &ls[kr][ng];
        d[0]  = v0.x; d[1]  = v0.y; d[2]  = v0.z; d[3]  = v0.w;
        d[4]  = v1.x; d[5]  = v1.y; d[6]  = v1.z; d[7]  = v1.w;
        d[8]  = v2.x; d[9]  = v2.y; d[10] = v2.z; d[11] = v2.w;
        d[12] = v3.x; d[13] = v3.y; d[14] = v3.z; d[15] = v3.w;
    }
    __syncthreads();
    int n = t >> 2, kg = (t & 3) * 16;
    u16 o[16];
#pragma unroll
    for (int j = 0; j < 16; ++j) o[j] = f2bf(ls[kg + j][n]);
    u16* dp = &dst[(size_t)(n0 + n) * K + k0 + kg];
    *(bf16x8*)dp       = *(bf16x8*)&o[0];
    *(bf16x8*)(dp + 8) = *(bf16x8*)&o[8];
}

// ---------------------------------------------------------------- grouped GEMM
// R17-verbatim body (measured best, reproduced twice: 566us). 128x128, BK=32,
// 4 waves 2x2, depth-3 rotation, counted vmcnt(8) + raw s_barrier, asm
// ds_read_b128 (alias-opaque), both-sides XOR swizzle (0 conflicts),
// XCD-group map. NEW (R22): for GEMM1's SHARED expert only, remap its 32
// groups x 32 slots into 16 super-tiles of 8x8 blocks (A 2MB + B 2MB = L2-
// resident, fetched once each; two time-consecutive groups per super-tile on
// one XCD) -- removes the 8MB-A-panel L2 thrash that is ~256MB of GEMM1's
// 543MB fabric traffic. Bijective; routed experts and GEMM2 unchanged.
// GEMM==1: A=xb gathered via lists (K=1024,N=4096), epi gelu->bf16 H.
// GEMM==2: A=H contiguous (K=4096,N=1024), epi +bias->f32 P.
template <int GEMM>
__global__ __launch_bounds__(256, 3)
void k_gemm(const u16* __restrict__ A, const u16* __restrict__ Bt,
            const float* __restrict__ be, const float* __restrict__ bsh,
            const int* __restrict__ counts, const int* __restrict__ offsets,
            const int* __restrict__ lists, void* __restrict__ Cg)
{
    constexpr int K  = (GEMM == 1) ? D_DIM : I_DIM;
    constexpr int N  = (GEMM == 1) ? I_DIM : D_DIM;
    constexpr int NT = N / 128;              // 32 / 8
    constexpr int nk = K / BK;               // 32 / 128 (both == 2 mod 3)

    const int bid = blockIdx.x;
    const int g    = ((bid >> 3) >> 5) * 8 + (bid & 7);
    const int slot = (bid >> 3) & 31;
    const int e    = g / NT;
    int mt = slot, nt = g % NT;
    if constexpr (GEMM == 1) {
        if (e == 8) {
            // 2D super-tile remap for the shared expert (see header comment).
            int gs = g - 8 * NT;             // [0,32)
            int st = 2 * (gs & 7) + ((gs >> 3) >> 1);   // [0,16)
            int h  = (gs >> 3) & 1;
            int idx = h * 32 + slot;         // [0,64)
            mt = (st >> 2) * 8 + (idx >> 3);
            nt = (st & 3) * 8 + (idx & 7);
        }
    }
    const int cnt = counts[e];
    if (mt * 128 >= cnt) return;             // block-uniform: before any barrier
    const int off = offsets[e];

    __shared__ __align__(16) u16 As0[4096], As1[4096], As2[4096];
    __shared__ __align__(16) u16 Bs0[4096], Bs1[4096], Bs2[4096];

    const int tid = threadIdx.x, w = tid >> 6, l = tid & 63;
    const int wu = __builtin_amdgcn_readfirstlane(w);
    const int wr = w >> 1, wc = w & 1;

    const int scol = ((l & 3) ^ ((l >> 3) & 3)) * 8;        // elements
    const uint32_t rch  = (uint32_t)(((l >> 4) ^ (((l & 15) >> 1) & 3)) << 4);
    const uint32_t aoff = (uint32_t)((wr * 64 + (l & 15)) * 64) + rch;
    const uint32_t boff = (uint32_t)((wc * 64 + (l & 15)) * 64) + rch;
    const uint32_t adr_a0 = (uint32_t)(uintptr_t)As0 + aoff;
    const uint32_t adr_a1 = (uint32_t)(uintptr_t)As1 + aoff;
    const uint32_t adr_a2 = (uint32_t)(uintptr_t)As2 + aoff;
    const uint32_t adr_b0 = (uint32_t)(uintptr_t)Bs0 + boff;
    const uint32_t adr_b1 = (uint32_t)(uintptr_t)Bs1 + boff;
    const uint32_t adr_b2 = (uint32_t)(uintptr_t)Bs2 + boff;

    const u16* Be = Bt + (size_t)e * N * K;
    const u16* aptr[2];
    const u16* bptr[2];
#pragma unroll
    for (int q = 0; q < 2; ++q) {
        int row = mt * 128 + w * 32 + q * 16 + (l >> 2);
        int srow;
        if constexpr (GEMM == 1) {
            if (e == 8) srow = row;          // shared expert: token id == row
            else        srow = lists[e * T_TOK + (row < cnt ? row : cnt - 1)];
        } else {
            srow = off + row;                // contiguous H rows
        }
        aptr[q] = A + (size_t)srow * K + scol;
        bptr[q] = Be + (size_t)(nt * 128 + w * 32 + q * 16 + (l >> 2)) * K + scol;
    }

    f32x4 zero = {0.f, 0.f, 0.f, 0.f};
    f32x4 acc[4][4];
#pragma unroll
    for (int m = 0; m < 4; ++m)
#pragma unroll
        for (int n = 0; n < 4; ++n) acc[m][n] = zero;

    auto STG = [&](u16* Asb, u16* Bsb, int kt) {
        const int ko = kt * BK;
#pragma unroll
        for (int q = 0; q < 2; ++q) {
            gl16(aptr[q] + ko, Asb + wu * 1024 + q * 512);
            gl16(bptr[q] + ko, Bsb + wu * 1024 + q * 512);
        }
    };
    auto RDM = [&](uint32_t aA, uint32_t aB, bool st, u16* sA, u16* sB, int knext) {
        bf16x8 fa[4], fb[4];
        DSR(fa[0], aA, 0);    DSR(fa[1], aA, 1024);
        DSR(fa[2], aA, 2048); DSR(fa[3], aA, 3072);
        DSR(fb[0], aB, 0);    DSR(fb[1], aB, 1024);
        DSR(fb[2], aB, 2048); DSR(fb[3], aB, 3072);
        WAIT_LG(0);
        __builtin_amdgcn_sched_barrier(0);
        __builtin_amdgcn_s_barrier();    // all waves done reading this buffer
        if (st) STG(sA, sB, knext);      // refill it; loads fly across barriers
        __builtin_amdgcn_s_setprio(1);
#pragma unroll
        for (int m = 0; m < 4; ++m)
#pragma unroll
            for (int n = 0; n < 4; ++n)
                acc[m][n] = __builtin_amdgcn_mfma_f32_16x16x32_bf16(fa[m], fb[n], acc[m][n], 0, 0, 0);
        __builtin_amdgcn_s_setprio(0);
    };

    STG(As0, Bs0, 0);
    STG(As1, Bs1, 1);
    STG(As2, Bs2, 2);
    for (int b = 0; b + 5 < nk; b += 3) {
        WAIT_VM(8); __builtin_amdgcn_s_barrier();
        RDM(adr_a0, adr_b0, true, As0, Bs0, b + 3);
        WAIT_VM(8); __builtin_amdgcn_s_barrier();
        RDM(adr_a1, adr_b1, true, As1, Bs1, b + 4);
        WAIT_VM(8); __builtin_amdgcn_s_barrier();
        RDM(adr_a2, adr_b2, true, As2, Bs2, b + 5);
    }
    WAIT_VM(8); __builtin_amdgcn_s_barrier();
    RDM(adr_a0, adr_b0, true, As0, Bs0, nk - 2);
    WAIT_VM(8); __builtin_amdgcn_s_barrier();
    RDM(adr_a1, adr_b1, true, As1, Bs1, nk - 1);
    WAIT_VM(8); __builtin_amdgcn_s_barrier();
    RDM(adr_a2, adr_b2, false, As2, Bs2, 0);
    WAIT_VM(4); __builtin_amdgcn_s_barrier();
    RDM(adr_a0, adr_b0, false, As0, Bs0, 0);
    WAIT_VM(0); __builtin_amdgcn_s_barrier();
    RDM(adr_a1, adr_b1, false, As1, Bs1, 0);

    // ---- epilogue.  D mapping: col = lane&15, row = (lane>>4)*4 + reg
    const float* bias = (e == 8) ? bsh : (be + (size_t)e * N);
#pragma unroll
    for (int m = 0; m < 4; ++m) {
        int pbase = mt * 128 + wr * 64 + m * 16 + (l >> 4) * 4;
#pragma unroll
        for (int n = 0; n < 4; ++n) {
            int gcol = nt * 128 + wc * 64 + n * 16 + (l & 15);
            float bv = bias[gcol];
#pragma unroll
            for (int r = 0; r < 4; ++r) {
                int pos = pbase + r;
                if (pos < cnt) {
                    float v = acc[m][n][r] + bv;
                    if constexpr (GEMM == 1)
                        ((u16*)Cg)[(size_t)(off + pos) * N + gcol] = f2bf(gelu_fast(v));
                    else
                        ((float*)Cg)[(size_t)(off + pos) * N + gcol] = v;
                }
            }
        }
    }
}

// ---------------------------------------------------------------- combine
__global__ __launch_bounds__(256) void k_combine(
    const float* __restrict__ x, const float* __restrict__ P,
    const int* __restrict__ offsets, const int* __restrict__ tok_e,
    const int* __restrict__ tok_pos, const float* __restrict__ tok_w,
    float* __restrict__ out)
{
    int t = blockIdx.x;
    int e0 = tok_e[2 * t], e1 = tok_e[2 * t + 1];
    int r0 = offsets[e0] + tok_pos[2 * t];
    int r1 = offsets[e1] + tok_pos[2 * t + 1];
    int rs = offsets[8] + t;
    float w0 = tok_w[2 * t], w1 = tok_w[2 * t + 1];
    int i = threadIdx.x * 4;

    float4 xv = *(const float4*)(x + (size_t)t * D_DIM + i);
    float4 ps = *(const float4*)(P + (size_t)rs * D_DIM + i);
    float4 p0 = *(const float4*)(P + (size_t)r0 * D_DIM + i);
    float4 p1 = *(const float4*)(P + (size_t)r1 * D_DIM + i);
    float4 o;
    o.x = xv.x + ps.x + w0 * p0.x + w1 * p1.x;
    o.y = xv.y + ps.y + w0 * p0.y + w1 * p1.y;
    o.z = xv.z + ps.z + w0 * p0.z + w1 * p1.z;
    o.w = xv.w + ps.w + w0 * p0.w + w1 * p1.w;
    *(float4*)(out + (size_t)t * D_DIM + i) = o;
}

// ---------------------------------------------------------------- launch
extern "C" void kernel_launch(void* const* d_in, const int* in_sizes, int n_in,
                              void* d_out, int out_size, void* d_ws, size_t ws_size,
                              hipStream_t stream)
{
    const float* x   = (const float*)d_in[0];
    const float* gw  = (const float*)d_in[1];
    const float* gb  = (const float*)d_in[2];
    const float* sw1 = (const float*)d_in[3];
    const float* sb1 = (const float*)d_in[4];
    const float* sw2 = (const float*)d_in[5];
    const float* sb2 = (const float*)d_in[6];
    const float* ew1 = (const float*)d_in[7];
    const float* eb1 = (const float*)d_in[8];
    const float* ew2 = (const float*)d_in[9];
    const float* eb2 = (const float*)d_in[10];

    char* w = (char*)d_ws;
    int* counts  = (int*)w;                       // 16 ints
    int* offsets = (int*)(w + 64);                // 16 ints
    int* tok_e   = (int*)(w + 2048);              // 2T ints
    int* tok_pos = tok_e + 2 * T_TOK;             // 2T ints
    float* tok_w = (float*)(tok_pos + 2 * T_TOK); // 2T floats
    int* lists   = (int*)(tok_w + 2 * T_TOK);     // 8T ints (routed only)

    size_t o = (size_t)1 << 20;                   // 1MB: small buffers above
    u16* xb  = (u16*)(w + o);                     // 4096 x 1024 bf16 (8MB)
    o += (size_t)T_TOK * D_DIM * 2;
    u16* H   = (u16*)(w + o);                     // 12288 x 4096 bf16 (96MB)
    o += (size_t)3 * T_TOK * I_DIM * 2;
    u16* Wt  = (u16*)(w + o);                     // 9 x 4096 x 1024 bf16 (72MB), W1t then W2t
    o += (size_t)NE * I_DIM * D_DIM * 2;
    float* P = (float*)(w + o);                   // 12288 x 1024 f32 (48MB)

    k_init<<<1, 64, 0, stream>>>(counts);

    // W1^T: f32 [K=1024][N=4096] -> bf16 [4096][1024], 9 slices in one launch
    k_transcast9<<<dim3(I_DIM / 64, D_DIM / 64, 9), 256, 0, stream>>>(
        ew1, sw1, Wt, D_DIM, I_DIM);

    // router (writes xb as a side product)
    k_router<<<T_TOK / 4, 256, 0, stream>>>(x, gw, gb, counts, lists, tok_e, tok_pos, tok_w, xb);
    k_prefix<<<1, 64, 0, stream>>>(counts, offsets);

    // GEMM1: H = gelu(Xg @ W1 + b1), N = I.  XCD-grouped 1-tile blocks,
    // shared-expert 2D super-tiling.
    k_gemm<1><<<NE * (I_DIM / 128) * 32, 256, 0, stream>>>(
        xb, Wt, eb1, sb1, counts, offsets, lists, (void*)H);

    // W2^T: f32 [K=4096][N=1024] -> bf16 [1024][4096]  (aliases W1t; stream-ordered)
    k_transcast9<<<dim3(D_DIM / 64, I_DIM / 64, 9), 256, 0, stream>>>(
        ew2, sw2, Wt, I_DIM, D_DIM);

    // GEMM2: P = H @ W2 + b2, N = D.  R15-verbatim 128x128, XCD-grouped.
    k_gemm<2><<<NE * (D_DIM / 128) * 32, 256, 0, stream>>>(
        H, Wt, eb2, sb2, counts, offsets, lists, (void*)P);

    k_combine<<<T_TOK, 256, 0, stream>>>(x, P, offsets, tok_e, tok_pos, tok_w, (float*)d_out);
}